// Round 6
// baseline (466.143 us; speedup 1.0000x reference)
//
#include <hip/hip_runtime.h>

// Problem constants
#define NB 2
#define NN 160
#define NPAIR (NN*NN)          // 25600
#define OUT_PAIRS_OFF 307200   // 3 * NB*NPAIR*2 fp32 elements before emb_pairs

typedef __attribute__((ext_vector_type(8))) short bf16x8;
typedef __attribute__((ext_vector_type(4))) float f32x4;

static __device__ __forceinline__ ushort f2bf(float x) {
    union { float f; uint u; } c; c.f = x;
    uint u = c.u;
    u += 0x7fffu + ((u >> 16) & 1u);   // RNE
    return (ushort)(u >> 16);
}

// ---------------------------------------------------------------------------
// Kernel 1: MFMA projections (validated structure from R2/R3 agreement):
//   proj[(t*2+s)*320 + p][f] = sum_c emb[p,c] * W1_t[s*768+c, f] (+ b1 at s=0)
// GEMM M=320, N=3072, K=768, mfma_f32_16x16x32_bf16; fp32 inputs converted
// to bf16 in registers (RNE). One wave per 32(M) x 16(N) tile.
// ---------------------------------------------------------------------------
__global__ __launch_bounds__(64) void proj_mfma_kernel(
    const float* __restrict__ geo, const float* __restrict__ app,
    const float* __restrict__ con,
    const float* __restrict__ w1c, const float* __restrict__ w1r,
    const float* __restrict__ w1l,
    const float* __restrict__ b1c, const float* __restrict__ b1r,
    const float* __restrict__ b1l,
    float* __restrict__ proj)
{
    const int lane = threadIdx.x;
    const int m0 = blockIdx.x * 32;      // 10 M-groups
    const int n0 = blockIdx.y * 16;      // 192 N-tiles
    const int t = n0 >> 10;              // head
    const int s = (n0 >> 9) & 1;         // W1 half (0: emb_j, 1: emb_i)
    const int f0 = n0 & 511;

    const float* w1 = (t == 0) ? w1c : ((t == 1) ? w1r : w1l);
    const float* b1 = (t == 0) ? b1c : ((t == 1) ? b1r : b1l);

    const int col = lane & 15;
    const int quad = lane >> 4;

    f32x4 acc0 = {0.f, 0.f, 0.f, 0.f};
    f32x4 acc1 = {0.f, 0.f, 0.f, 0.f};

    const float* wbase = w1 + (size_t)(s * 768) * 512 + f0 + col;
    const int p0 = m0 + col;       // A rows, subtile 0
    const int p1 = p0 + 16;        // subtile 1

    for (int k0 = 0; k0 < 768; k0 += 32) {
        const int klane = k0 + quad * 8;        // lane's 8 consecutive k's
        const int mod = klane >> 8;             // modality (never crosses)
        const int off = klane & 255;
        const float* src = (mod == 0) ? geo : ((mod == 1) ? app : con);

        const float4 a0lo = *(const float4*)(src + (size_t)p0 * 256 + off);
        const float4 a0hi = *(const float4*)(src + (size_t)p0 * 256 + off + 4);
        const float4 a1lo = *(const float4*)(src + (size_t)p1 * 256 + off);
        const float4 a1hi = *(const float4*)(src + (size_t)p1 * 256 + off + 4);

        bf16x8 af0, af1, bfrag;
        af0[0] = (short)f2bf(a0lo.x); af0[1] = (short)f2bf(a0lo.y);
        af0[2] = (short)f2bf(a0lo.z); af0[3] = (short)f2bf(a0lo.w);
        af0[4] = (short)f2bf(a0hi.x); af0[5] = (short)f2bf(a0hi.y);
        af0[6] = (short)f2bf(a0hi.z); af0[7] = (short)f2bf(a0hi.w);
        af1[0] = (short)f2bf(a1lo.x); af1[1] = (short)f2bf(a1lo.y);
        af1[2] = (short)f2bf(a1lo.z); af1[3] = (short)f2bf(a1lo.w);
        af1[4] = (short)f2bf(a1hi.x); af1[5] = (short)f2bf(a1hi.y);
        af1[6] = (short)f2bf(a1hi.z); af1[7] = (short)f2bf(a1hi.w);

        const float* wp = wbase + (size_t)klane * 512;
        #pragma unroll
        for (int j = 0; j < 8; ++j) bfrag[j] = (short)f2bf(wp[(size_t)j * 512]);

        acc0 = __builtin_amdgcn_mfma_f32_16x16x32_bf16(af0, bfrag, acc0, 0, 0, 0);
        acc1 = __builtin_amdgcn_mfma_f32_16x16x32_bf16(af1, bfrag, acc1, 0, 0, 0);
    }

    float bias = 0.f;
    if (s == 0) bias = b1[f0 + col];

    const size_t base = (size_t)(t * 2 + s) * 320 * 512 + f0 + col;
    #pragma unroll
    for (int r = 0; r < 4; ++r) {
        proj[base + (size_t)(m0 + quad * 4 + r) * 512]      = acc0[r] + bias;
        proj[base + (size_t)(m0 + 16 + quad * 4 + r) * 512] = acc1[r] + bias;
    }
}

// ---------------------------------------------------------------------------
// Kernel 2 (fused): per 8x8 pair tile:
//   (a) stream the tile's 64 emb_pairs rows (fp32 passthrough, 393 KB/block)
//   (b) 3 heads: d = (b2[1]-b2[0]) + sum_f relu(P1[j,f]+P2[i,f])*(W2[f,1]-W2[f,0])
//       probs = (sigmoid(-d), sigmoid(d)) -> float2 store
// Head compute hides under the store-queue drain (write-BW bound).
// ---------------------------------------------------------------------------
__global__ __launch_bounds__(64) void fused_kernel(
    const float* __restrict__ geo, const float* __restrict__ app,
    const float* __restrict__ con,
    const float* __restrict__ proj,
    const float* __restrict__ w2c, const float* __restrict__ b2c,
    const float* __restrict__ w2r, const float* __restrict__ b2r,
    const float* __restrict__ w2l, const float* __restrict__ b2l,
    float* __restrict__ out)
{
    __shared__ float P1s[8][516];   // +4 pad
    __shared__ float P2s[8][516];
    __shared__ float wds[512];

    const int tid = threadIdx.x;
    const int bid = blockIdx.x;
    const int b   = bid / 400;
    const int rem = bid - b * 400;
    const int it  = rem / 20;
    const int jt  = rem - it * 20;
    const int i0 = it * 8, j0 = jt * 8;
    const int ii = tid >> 3, jj = tid & 7;

    // ---- (a) emb_pairs streaming for this tile ----
    // row (b, i*160+j) = [emb[b,j] (768 fp32), emb[b,i] (768 fp32)]
    float4* pout = (float4*)(out + OUT_PAIRS_OFF);
    for (int r8 = 0; r8 < 8; ++r8) {          // i-row within tile
        #pragma unroll
        for (int jl = 0; jl < 8; ++jl) {      // j-row within tile
            const int row = b * 25600 + (i0 + r8) * 160 + (j0 + jl);
            for (int u = tid; u < 384; u += 64) {   // 6 iters, lane-coalesced
                const int half = (u >= 192) ? 1 : 0;       // uniform per iter
                const int cc   = u - half * 192;
                const int m    = cc >> 6;                  // uniform per iter
                const int off  = cc & 63;
                const int pt   = half ? (i0 + r8) : (j0 + jl);
                const float* src = ((m == 0) ? geo : (m == 1) ? app : con)
                                   + ((size_t)(b * 160 + pt)) * 256 + off * 4;
                pout[(size_t)row * 384 + u] = *(const float4*)src;
            }
        }
    }

    // ---- (b) three heads ----
    #pragma unroll
    for (int t = 0; t < 3; ++t) {
        const float* w2 = (t == 0) ? w2c : ((t == 1) ? w2r : w2l);
        const float* b2 = (t == 0) ? b2c : ((t == 1) ? b2r : b2l);

        for (int u = tid; u < 2048; u += 64) {
            const int tile = u >> 10;
            const int r    = (u >> 7) & 7;
            const int f4   = u & 127;
            const int p    = b * 160 + (tile ? (i0 + r) : (j0 + r));
            const float4 v = *(const float4*)(
                proj + ((size_t)((t * 2 + tile) * 320 + p)) * 512 + f4 * 4);
            float* dst = tile ? &P2s[r][f4 * 4] : &P1s[r][f4 * 4];
            *(float4*)dst = v;
        }
        for (int u = tid; u < 512; u += 64)
            wds[u] = w2[u * 2 + 1] - w2[u * 2];
        __syncthreads();

        float d = b2[1] - b2[0];
        for (int f = 0; f < 512; f += 4) {
            const float4 p1 = *(const float4*)&P1s[jj][f];
            const float4 p2 = *(const float4*)&P2s[ii][f];
            const float4 wd = *(const float4*)&wds[f];
            d += fmaxf(p1.x + p2.x, 0.f) * wd.x;
            d += fmaxf(p1.y + p2.y, 0.f) * wd.y;
            d += fmaxf(p1.z + p2.z, 0.f) * wd.z;
            d += fmaxf(p1.w + p2.w, 0.f) * wd.w;
        }

        // softmax(a0,a1) == (sigmoid(-d), sigmoid(d)), d = a1-a0
        const float e   = __expf(-fabsf(d));
        const float inv = 1.f / (1.f + e);
        const float phi = inv;          // prob of the larger logit
        const float plo = e * inv;
        float2 o;
        o.x = (d >= 0.f) ? plo : phi;
        o.y = (d >= 0.f) ? phi : plo;

        const int pr = b * 25600 + (i0 + ii) * 160 + (j0 + jj);
        ((float2*)out)[t * 51200 + pr] = o;
        __syncthreads();
    }
}

extern "C" void kernel_launch(void* const* d_in, const int* in_sizes, int n_in,
                              void* d_out, int out_size, void* d_ws, size_t ws_size,
                              hipStream_t stream)
{
    const float* geo = (const float*)d_in[0];
    const float* app = (const float*)d_in[1];
    const float* con = (const float*)d_in[2];
    const float* w1c = (const float*)d_in[3];
    const float* b1c = (const float*)d_in[4];
    const float* w2c = (const float*)d_in[5];
    const float* b2c = (const float*)d_in[6];
    const float* w1r = (const float*)d_in[7];
    const float* b1r = (const float*)d_in[8];
    const float* w2r = (const float*)d_in[9];
    const float* b2r = (const float*)d_in[10];
    const float* w1l = (const float*)d_in[11];
    const float* b1l = (const float*)d_in[12];
    const float* w2l = (const float*)d_in[13];
    const float* b2l = (const float*)d_in[14];

    float* out  = (float*)d_out;
    float* proj = (float*)d_ws;   // 6*320*512 fp32 = 3.93 MB scratch

    // 1) MFMA projections (GEMM 320 x 3072 x 768, bf16 inputs via reg-cvt)
    proj_mfma_kernel<<<dim3(10, 192), 64, 0, stream>>>(
        geo, app, con, w1c, w1r, w1l, b1c, b1r, b1l, proj);

    // 2) fused: emb_pairs stream (314.6 MB) + 3 softmax heads
    fused_kernel<<<800, 64, 0, stream>>>(
        geo, app, con, proj, w2c, b2c, w2r, b2r, w2l, b2l, out);
}